// Round 25
// baseline (168.674 us; speedup 1.0000x reference)
//
#include <hip/hip_runtime.h>
#include <hip/hip_fp8.h>

// ---------------------------------------------------------------------------
// GraphSAGE forward: 3x SAGEConv(mean) + ReLU(1,2) + final 128->2 projection.
// Round-23 proven config (154.6us): BM=32 fused gather+GEMM, fp8 layer-2
// gather (HW cvt), 4-edge batch + index prefetch, setprio K-loop, LDS-staged
// coalesced epilogue, atomic-free scatter, collapsed layer-3.
// This round: __launch_bounds__(256,6) on fused kernels (96-VGPR cap ->
// 6 blocks/CU vs 4; gather is latency-bound, more waves hide more).
// BM=16 experiment (R24) reverted: W-traffic doubling beat concurrency gain.
// ---------------------------------------------------------------------------

constexpr int D_IN  = 128;
constexpr int D_HID = 256;

typedef __attribute__((ext_vector_type(8))) short short8x;
typedef __attribute__((ext_vector_type(4))) float f32x4;
typedef __attribute__((ext_vector_type(2))) float f32x2;

__device__ inline unsigned bf16_rne(float f) {
    unsigned u = __float_as_uint(f);
    return (u + 0x7fffu + ((u >> 16) & 1u)) >> 16;
}

// ---------------- fused setup ----------------

__device__ inline void prep_wt_elem(const float* __restrict__ Wl,
                                    const float* __restrict__ Wr,
                                    int K1, int K2, int Nc, int i,
                                    short* __restrict__ WTh) {
    const int KE = K1 + K2;
    const int KSTEPS = KE / 32;
    int e = i & 7;
    int t = i >> 3;
    int l = t & 63;
    int t2 = t >> 6;
    int k32 = t2 % KSTEPS;
    int n16 = t2 / KSTEPS;
    int n = n16 * 16 + (l & 15);
    int k = k32 * 32 + (l >> 4) * 8 + e;
    float w = (k < K1) ? Wl[(size_t)k * Nc + n] : Wr[(size_t)(k - K1) * Nc + n];
    WTh[i] = (short)bf16_rne(w);
}

__global__ __launch_bounds__(256) void setup_kernel(
    const float* __restrict__ Wl1, const float* __restrict__ Wr1,
    short* __restrict__ wt1h,
    const float* __restrict__ Wl2, const float* __restrict__ Wr2,
    short* __restrict__ wt2h,
    const float* __restrict__ Wl3, const float* __restrict__ Wr3,
    const float* __restrict__ b3, const float* __restrict__ Wout,
    const float* __restrict__ bout, float* __restrict__ Wc, float* __restrict__ bc,
    const float* __restrict__ x, unsigned short* __restrict__ xb,
    const int* __restrict__ dst, int* __restrict__ cnt, int* __restrict__ erank,
    int Nn, int E) {
    const int gtid = blockIdx.x * blockDim.x + threadIdx.x;
    const int gs = gridDim.x * blockDim.x;

    const int n8 = Nn * D_IN / 8;
    for (int i = gtid; i < n8; i += gs) {
        const float4* p = (const float4*)(x + (size_t)i * 8);
        float4 v0 = p[0], v1 = p[1];
        float f[8] = {v0.x, v0.y, v0.z, v0.w, v1.x, v1.y, v1.z, v1.w};
        unsigned h[8];
        #pragma unroll
        for (int j = 0; j < 8; ++j) h[j] = bf16_rne(f[j]);
        uint4 qh;
        qh.x = h[0] | (h[1] << 16); qh.y = h[2] | (h[3] << 16);
        qh.z = h[4] | (h[5] << 16); qh.w = h[6] | (h[7] << 16);
        *(uint4*)(xb + (size_t)i * 8) = qh;
    }

    // degree count; atomic return value = within-bucket rank (free)
    for (int i = gtid; i < E; i += gs)
        erank[i] = atomicAdd(&cnt[dst[i]], 1);

    for (int i = gtid; i < 256 * 256; i += gs)
        prep_wt_elem(Wl1, Wr1, 128, 128, 256, i, wt1h);
    for (int i = gtid; i < 256 * 512; i += gs)
        prep_wt_elem(Wl2, Wr2, 256, 256, 256, i, wt2h);

    if (gtid < 1024 * 16) {
        int d = gtid >> 4, sl = gtid & 15;
        int hh = d >> 2, c = d & 3;
        const float* Ws = (c < 2) ? Wl3 : Wr3;
        int o = c & 1;
        float s = 0.f;
        #pragma unroll
        for (int e = 0; e < 8; ++e) {
            int k = sl * 8 + e;
            s += Ws[hh * 128 + k] * Wout[k * 2 + o];
        }
        #pragma unroll
        for (int mk = 8; mk >= 1; mk >>= 1) s += __shfl_xor(s, mk, 16);
        if (sl == 0) Wc[d] = s;
    }
    if (gtid >= 16384 && gtid < 16416) {
        int o = (gtid >> 4) & 1, sl = gtid & 15;
        float s = 0.f;
        #pragma unroll
        for (int e = 0; e < 8; ++e) {
            int k = sl * 8 + e;
            s += b3[k] * Wout[k * 2 + o];
        }
        #pragma unroll
        for (int mk = 8; mk >= 1; mk >>= 1) s += __shfl_xor(s, mk, 16);
        if (sl == 0) bc[o] = s + bout[o];
    }
}

// ---------------- CSR scan + atomic-free scatter ----------------

__global__ __launch_bounds__(1024) void scan_local_kernel(
    const int* __restrict__ cnt, int* __restrict__ row_ptr,
    int* __restrict__ bsums, int Nn) {
    __shared__ int wsum[16];
    const int tid = threadIdx.x, lane = tid & 63, wid = tid >> 6;
    const int idx0 = blockIdx.x * 4096 + tid * 4;
    int v[4];
    #pragma unroll
    for (int j = 0; j < 4; ++j) {
        int idx = idx0 + j;
        v[j] = (idx < Nn) ? cnt[idx] : 0;
    }
    int s = v[0] + v[1] + v[2] + v[3];
    int xi = s;
    #pragma unroll
    for (int o = 1; o < 64; o <<= 1) {
        int t = __shfl_up(xi, o, 64);
        if (lane >= o) xi += t;
    }
    if (lane == 63) wsum[wid] = xi;
    __syncthreads();
    if (wid == 0) {
        int t = (lane < 16) ? wsum[lane] : 0;
        #pragma unroll
        for (int o = 1; o < 16; o <<= 1) {
            int u = __shfl_up(t, o, 64);
            if (lane >= o) t += u;
        }
        if (lane < 16) wsum[lane] = t;
    }
    __syncthreads();
    int off = (wid ? wsum[wid - 1] : 0) + xi - s;
    int run = off;
    #pragma unroll
    for (int j = 0; j < 4; ++j) {
        int idx = idx0 + j;
        if (idx <= Nn) row_ptr[idx] = run;
        run += v[j];
    }
    if (tid == 0) bsums[blockIdx.x] = wsum[15];
}

__global__ __launch_bounds__(1024) void scan_add_kernel(
    int* __restrict__ row_ptr, const int* __restrict__ bsums, int Nn) {
    __shared__ int sbase;
    const int b = blockIdx.x;
    if (threadIdx.x == 0) {
        int s = 0;
        for (int i = 0; i < b; ++i) s += bsums[i];
        sbase = s;
    }
    __syncthreads();
    const int base = sbase;
    const int idx0 = b * 4096 + threadIdx.x * 4;
    #pragma unroll
    for (int j = 0; j < 4; ++j) {
        int idx = idx0 + j;
        if (idx <= Nn) row_ptr[idx] += base;
    }
}

// atomic-free: position = row_ptr[dst] + erank (rank saved during count).
__global__ __launch_bounds__(256) void scatter_kernel(
    const int* __restrict__ src, const int* __restrict__ dst,
    const int* __restrict__ row_ptr, const int* __restrict__ erank,
    int* __restrict__ esrc, int E) {
    int i0 = (blockIdx.x * blockDim.x + threadIdx.x) * 4;
    if (i0 >= E) return;
    int n = E - i0; if (n > 4) n = 4;
    int s[4], d[4], r[4], b[4];
    for (int j = 0; j < n; ++j) { s[j] = src[i0 + j]; d[j] = dst[i0 + j]; r[j] = erank[i0 + j]; }
    for (int j = 0; j < n; ++j) b[j] = row_ptr[d[j]];
    for (int j = 0; j < n; ++j) esrc[b[j] + r[j]] = s[j];
}

// ---------------- gather decode helpers ----------------

__device__ inline void addbf8(const uint4& q, float* a) {
    a[0] += __uint_as_float(q.x << 16); a[1] += __uint_as_float(q.x & 0xFFFF0000u);
    a[2] += __uint_as_float(q.y << 16); a[3] += __uint_as_float(q.y & 0xFFFF0000u);
    a[4] += __uint_as_float(q.z << 16); a[5] += __uint_as_float(q.z & 0xFFFF0000u);
    a[6] += __uint_as_float(q.w << 16); a[7] += __uint_as_float(q.w & 0xFFFF0000u);
}

__device__ inline void addf8w(unsigned u, float* a) {
    f32x2 lo = __builtin_amdgcn_cvt_pk_f32_fp8((int)u, false);
    f32x2 hi = __builtin_amdgcn_cvt_pk_f32_fp8((int)u, true);
    a[0] += lo.x; a[1] += lo.y; a[2] += hi.x; a[3] += hi.y;
}

__device__ inline void addf8x16(const uint4& q, float* a) {
    addf8w(q.x, a + 0); addf8w(q.y, a + 4); addf8w(q.z, a + 8); addf8w(q.w, a + 12);
}

// ---------------- FUSED gather + bf16 MFMA GEMM, BM=32 ----------------
// Phase 1: gather-mean into sA[:, 0:K1] (bf16, XOR-swizzled chunks), 4-edge
// batched with next-batch index prefetch. Phase 2: self rows. One barrier.
// Phase 3: barrier-free K-loop (setprio(1)), B reg-prefetched 1 step ahead.
// Epilogue (!TU): LDS-staged coalesced write-out; (TU): sRed overlay.
// Swizzle: chunk c (16B) of row r stored at p = (c&~7) | ((c&7)^(r&7)).

template <int K1, int K2, int N, bool RELU, bool TU, bool F8G, bool F8OUT>
__global__ __launch_bounds__(256, 6) void fused_gemm_kernel(
    const void* __restrict__ gsrc, const unsigned short* __restrict__ self,
    const int* __restrict__ row_ptr, const int* __restrict__ esrc,
    const short8x* __restrict__ WTh, const float* __restrict__ bias,
    unsigned short* __restrict__ C, unsigned char* __restrict__ C8,
    const float* __restrict__ Wc, const float* __restrict__ bc,
    float* __restrict__ tuout, int M) {
    constexpr int KEFF = K1 + K2;
    constexpr int KS32 = KEFF / 32;
    constexpr int NC1 = K1 / 8;       // gather-half chunks per row
    constexpr int NC2 = K2 / 8;       // self-half chunks per row
    __shared__ __attribute__((aligned(16))) unsigned short sA[32][KEFF];
    __shared__ __attribute__((aligned(16))) unsigned char sF8[F8OUT ? 32 * N : 16];
    float4* sRed = (float4*)&sA[0][0];          // TU overlay (after K-loop)
    unsigned short* sC = &sA[0][0];             // !TU overlay (after K-loop)
    const int tid = threadIdx.x, lane = tid & 63, wid = tid >> 6;
    const int bm = blockIdx.x * 32;

    // ---- phase 1: gather-mean into sA[:, 0:K1] (16 lanes per node) ----
    #pragma unroll
    for (int pass = 0; pass < 2; ++pass) {
        const int nl = pass * 16 + wid * 4 + (lane >> 4);
        const int node = bm + nl;
        const int sl = lane & 15;
        if constexpr (!F8G) {
            float a0[8] = {}, a1[8] = {}, a2[8] = {}, a3[8] = {};
            float inv = 1.0f;
            if (node < M) {
                int beg = row_ptr[node], end = row_ptr[node + 1];
                const unsigned short* xg = (const unsigned short*)gsrc;
                int e = beg;
                const int nb4 = (end - beg) >> 2;
                if (nb4 > 0) {
                    int s0 = esrc[e], s1 = esrc[e + 1], s2 = esrc[e + 2], s3 = esrc[e + 3];
                    for (int b = 0; b < nb4; ++b) {
                        int t0 = s0, t1 = s1, t2 = s2, t3 = s3;
                        int en = e + 4;
                        if (b + 1 < nb4) {   // prefetch next batch indices
                            s0 = esrc[en]; s1 = esrc[en + 1];
                            s2 = esrc[en + 2]; s3 = esrc[en + 3];
                        }
                        uint4 q0 = *(const uint4*)(xg + (size_t)t0 * K1 + sl * 8);
                        uint4 q1 = *(const uint4*)(xg + (size_t)t1 * K1 + sl * 8);
                        uint4 q2 = *(const uint4*)(xg + (size_t)t2 * K1 + sl * 8);
                        uint4 q3 = *(const uint4*)(xg + (size_t)t3 * K1 + sl * 8);
                        addbf8(q0, a0); addbf8(q1, a1); addbf8(q2, a2); addbf8(q3, a3);
                        e = en;
                    }
                }
                for (; e < end; ++e) {
                    uint4 q0 = *(const uint4*)(xg + (size_t)esrc[e] * K1 + sl * 8);
                    addbf8(q0, a0);
                }
                inv = 1.0f / fmaxf((float)(end - beg), 1.0f);
            }
            unsigned h[8];
            #pragma unroll
            for (int i = 0; i < 8; ++i)
                h[i] = bf16_rne((a0[i] + a1[i] + a2[i] + a3[i]) * inv);
            uint4 qh;
            qh.x = h[0] | (h[1] << 16); qh.y = h[2] | (h[3] << 16);
            qh.z = h[4] | (h[5] << 16); qh.w = h[6] | (h[7] << 16);
            int p = (sl & 8) | ((sl & 7) ^ (nl & 7));
            *(uint4*)&sA[nl][p * 8] = qh;
        } else {
            float a0[16] = {}, a1[16] = {};
            float inv = 1.0f;
            if (node < M) {
                int beg = row_ptr[node], end = row_ptr[node + 1];
                const unsigned char* xg = (const unsigned char*)gsrc;
                int e = beg;
                const int nb4 = (end - beg) >> 2;
                if (nb4 > 0) {
                    int s0 = esrc[e], s1 = esrc[e + 1], s2 = esrc[e + 2], s3 = esrc[e + 3];
                    for (int b = 0; b < nb4; ++b) {
                        int t0 = s0, t1 = s1, t2 = s2, t3 = s3;
                        int en = e + 4;
                        if (b + 1 < nb4) {   // prefetch next batch indices
                            s0 = esrc[en]; s1 = esrc[en + 1];
                            s2 = esrc[en + 2]; s3 = esrc[en + 3];
                        }
                        uint4 q0 = *(const uint4*)(xg + (size_t)t0 * K1 + sl * 16);
                        uint4 q1 = *(const uint4*)(xg + (size_t)t1 * K1 + sl * 16);
                        uint4 q2 = *(const uint4*)(xg + (size_t)t2 * K1 + sl * 16);
                        uint4 q3 = *(const uint4*)(xg + (size_t)t3 * K1 + sl * 16);
                        addf8x16(q0, a0); addf8x16(q1, a1);
                        addf8x16(q2, a0); addf8x16(q3, a1);
                        e = en;
                    }
                }
                for (; e < end; ++e) {
                    uint4 q0 = *(const uint4*)(xg + (size_t)esrc[e] * K1 + sl * 16);
                    addf8x16(q0, a0);
                }
                inv = 1.0f / fmaxf((float)(end - beg), 1.0f);
            }
            unsigned h[16];
            #pragma unroll
            for (int i = 0; i < 16; ++i)
                h[i] = bf16_rne((a0[i] + a1[i]) * inv);
            uint4 qa, qb;
            qa.x = h[0]  | (h[1]  << 16); qa.y = h[2]  | (h[3]  << 16);
            qa.z = h[4]  | (h[5]  << 16); qa.w = h[6]  | (h[7]  << 16);
            qb.x = h[8]  | (h[9]  << 16); qb.y = h[10] | (h[11] << 16);
            qb.z = h[12] | (h[13] << 16); qb.w = h[14] | (h[15] << 16);
            int c0 = sl * 2, c1 = sl * 2 + 1;
            int p0 = (c0 & ~7) | ((c0 & 7) ^ (nl & 7));
            int p1 = (c1 & ~7) | ((c1 & 7) ^ (nl & 7));
            *(uint4*)&sA[nl][p0 * 8] = qa;
            *(uint4*)&sA[nl][p1 * 8] = qb;
        }
    }

    // ---- phase 2: self rows into sA[:, K1:] ----
    {
        const int row = tid >> 3, sub = tid & 7;
        int grow = bm + row; if (grow >= M) grow = M - 1;
        #pragma unroll
        for (int i = 0; i < NC2 / 8; ++i) {
            int cg = sub + 8 * i;
            uint4 v = *(const uint4*)(self + (size_t)grow * K2 + cg * 8);
            int c = NC1 + cg;
            int p = (c & ~7) | ((c & 7) ^ (row & 7));
            *(uint4*)&sA[row][p * 8] = v;
        }
    }
    __syncthreads();

    // ---- phase 3: barrier-free K-loop (MFMA priority boost) ----
    auto loadB = [&](int ks, short8x* bh) {
        #pragma unroll
        for (int n = 0; n < 4; ++n)
            bh[n] = WTh[((size_t)(wid * 4 + n) * KS32 + ks) * 64 + lane];
    };

    f32x4 acc[2][4];
    #pragma unroll
    for (int m = 0; m < 2; ++m)
        #pragma unroll
        for (int n = 0; n < 4; ++n)
            acc[m][n] = (f32x4){0.f, 0.f, 0.f, 0.f};

    short8x bhC[4], bhN[4];
    loadB(0, bhC);

    __builtin_amdgcn_s_setprio(1);
    #pragma unroll
    for (int ks = 0; ks < KS32; ++ks) {
        if (ks + 1 < KS32) loadB(ks + 1, bhN);
        short8x a[2];
        #pragma unroll
        for (int m = 0; m < 2; ++m) {
            const int row = m * 16 + (lane & 15);
            const int c = ks * 4 + (lane >> 4);
            const int p = (c & ~7) | ((c & 7) ^ (lane & 7));   // row&7 == lane&7
            a[m] = *(const short8x*)&sA[row][p * 8];
        }
        #pragma unroll
        for (int m = 0; m < 2; ++m)
            #pragma unroll
            for (int n = 0; n < 4; ++n)
                acc[m][n] = __builtin_amdgcn_mfma_f32_16x16x32_bf16(a[m], bhC[n], acc[m][n], 0, 0, 0);
        if (ks + 1 < KS32) {
            #pragma unroll
            for (int n = 0; n < 4; ++n) bhC[n] = bhN[n];  // renamed by unroll
        }
    }
    __builtin_amdgcn_s_setprio(0);

    float bv[4];
    #pragma unroll
    for (int n = 0; n < 4; ++n) bv[n] = bias[wid * 64 + n * 16 + (lane & 15)];

    if constexpr (!TU) {
        __syncthreads();   // sA reads done; overlay as staged C tile
        #pragma unroll
        for (int n = 0; n < 4; ++n) {
            const int col = wid * 64 + n * 16 + (lane & 15);
            #pragma unroll
            for (int m = 0; m < 2; ++m) {
                #pragma unroll
                for (int j = 0; j < 4; ++j) {
                    int rl = m * 16 + (lane >> 4) * 4 + j;
                    float v = acc[m][n][j] + bv[n];
                    if (RELU) v = fmaxf(v, 0.f);
                    sC[rl * N + col] = (unsigned short)bf16_rne(v);
                    if (F8OUT) {
                        int pk = __builtin_amdgcn_cvt_pk_fp8_f32(v, v, 0, false);
                        sF8[rl * N + col] = (unsigned char)(pk & 0xff);
                    }
                }
            }
        }
        __syncthreads();
        // coalesced full-line write-out of the contiguous block tile
        const int vrows = (M - bm < 32) ? (M - bm) : 32;
        const int tot = vrows * N;                    // elements
        const size_t base = (size_t)bm * N;
        for (int i = tid * 8; i < tot; i += 256 * 8)
            *(uint4*)(C + base + i) = *(const uint4*)(sC + i);
        if (F8OUT) {
            for (int i = tid * 16; i < tot; i += 256 * 16)
                *(uint4*)(C8 + base + i) = *(const uint4*)(sF8 + i);
        }
    } else {
        float4 wcv[4];
        #pragma unroll
        for (int n = 0; n < 4; ++n)
            wcv[n] = *(const float4*)(Wc + (size_t)(wid * 64 + n * 16 + (lane & 15)) * 4);
        __syncthreads();   // all waves done reading sA before sRed overlay write
        #pragma unroll
        for (int m = 0; m < 2; ++m) {
            #pragma unroll
            for (int j = 0; j < 4; ++j) {
                float4 p = make_float4(0.f, 0.f, 0.f, 0.f);
                #pragma unroll
                for (int n = 0; n < 4; ++n) {
                    float v = acc[m][n][j] + bv[n];
                    if (RELU) v = fmaxf(v, 0.f);
                    p.x += v * wcv[n].x; p.y += v * wcv[n].y;
                    p.z += v * wcv[n].z; p.w += v * wcv[n].w;
                }
                #pragma unroll
                for (int mk = 8; mk >= 1; mk >>= 1) {
                    p.x += __shfl_xor(p.x, mk, 64);
                    p.y += __shfl_xor(p.y, mk, 64);
                    p.z += __shfl_xor(p.z, mk, 64);
                    p.w += __shfl_xor(p.w, mk, 64);
                }
                if ((lane & 15) == 0)
                    sRed[wid * 32 + m * 16 + (lane >> 4) * 4 + j] = p;
            }
        }
        __syncthreads();
        if (tid < 32) {
            int row = bm + tid;
            float4 a = sRed[0 * 32 + tid], b2 = sRed[1 * 32 + tid];
            float4 c2 = sRed[2 * 32 + tid], d2 = sRed[3 * 32 + tid];
            float4 t;
            t.x = a.x + b2.x + c2.x + d2.x;
            t.y = a.y + b2.y + c2.y + d2.y;
            t.z = a.z + b2.z + c2.z + d2.z + bc[0];
            t.w = a.w + b2.w + c2.w + d2.w + bc[1];
            if (row < M) *(float4*)(tuout + (size_t)row * 4) = t;
        }
    }
}

// ---------------- out_i = mean_j t_j + u_i  (D=2 gather, L2-resident) ------

__global__ __launch_bounds__(256) void final_out_kernel(
    const float* __restrict__ tu, const int* __restrict__ row_ptr,
    const int* __restrict__ esrc, float* __restrict__ out, int Nn) {
    int stride = gridDim.x * blockDim.x;
    for (int i = blockIdx.x * blockDim.x + threadIdx.x; i < Nn; i += stride) {
        int beg = row_ptr[i], end = row_ptr[i + 1];
        float s0 = 0.f, s1 = 0.f;
        for (int e = beg; e < end; ++e) {
            int s = esrc[e];
            float2 tv = *(const float2*)(tu + (size_t)s * 4);
            s0 += tv.x; s1 += tv.y;
        }
        float inv = 1.0f / fmaxf((float)(end - beg), 1.0f);
        float u0 = tu[(size_t)i * 4 + 2], u1 = tu[(size_t)i * 4 + 3];
        *(float2*)(out + (size_t)i * 2) = make_float2(s0 * inv + u0, s1 * inv + u1);
    }
}

// ---------------- launch ----------------

extern "C" void kernel_launch(void* const* d_in, const int* in_sizes, int n_in,
                              void* d_out, int out_size, void* d_ws, size_t ws_size,
                              hipStream_t stream) {
    const float* x    = (const float*)d_in[0];
    const int*   ei   = (const int*)d_in[1];
    const float* Wl1  = (const float*)d_in[2];
    const float* Wr1  = (const float*)d_in[3];
    const float* b1   = (const float*)d_in[4];
    const float* Wl2  = (const float*)d_in[5];
    const float* Wr2  = (const float*)d_in[6];
    const float* b2   = (const float*)d_in[7];
    const float* Wl3  = (const float*)d_in[8];
    const float* Wr3  = (const float*)d_in[9];
    const float* b3   = (const float*)d_in[10];
    const float* Wout = (const float*)d_in[11];
    const float* bout = (const float*)d_in[12];

    const int Nn = in_sizes[0] / D_IN;     // 50000
    const int E  = in_sizes[1] / 2;        // 600000

    char* ws = (char*)d_ws;
    size_t off = 0;
    auto alloc = [&](size_t b) { size_t o = off; off = (off + b + 255) & ~(size_t)255; return o; };

    unsigned short* xb    = (unsigned short*)(ws + alloc((size_t)Nn * D_IN * 2));
    int*   row_ptr = (int*)(ws + alloc((size_t)(Nn + 1) * 4));
    int*   cnt     = (int*)(ws + alloc((size_t)Nn * 4));
    int*   erank   = (int*)(ws + alloc((size_t)E * 4));
    int*   bsums   = (int*)(ws + alloc((size_t)256 * 4));
    int*   esrc    = (int*)(ws + alloc((size_t)E * 4));
    unsigned short* h1b   = (unsigned short*)(ws + alloc((size_t)Nn * D_HID * 2));
    unsigned char*  h1f8  = (unsigned char*)(ws + alloc((size_t)Nn * D_HID));
    float* tu      = (float*)(ws + alloc((size_t)Nn * 4 * 4));
    float* Wc      = (float*)(ws + alloc((size_t)256 * 4 * 4));
    float* bc      = (float*)(ws + alloc((size_t)2 * 4));
    short* wt1h    = (short*)(ws + alloc((size_t)256 * 256 * 2));
    short* wt2h    = (short*)(ws + alloc((size_t)256 * 512 * 2));

    const int* src = ei;
    const int* dst = ei + E;

    hipMemsetAsync(cnt, 0, (size_t)Nn * 4, stream);

    setup_kernel<<<2048, 256, 0, stream>>>(
        Wl1, Wr1, wt1h, Wl2, Wr2, wt2h,
        Wl3, Wr3, b3, Wout, bout, Wc, bc,
        x, xb, dst, cnt, erank, Nn, E);

    const int nb = (Nn + 1 + 4095) / 4096;   // 13
    scan_local_kernel<<<nb, 1024, 0, stream>>>(cnt, row_ptr, bsums, Nn);
    scan_add_kernel<<<nb, 1024, 0, stream>>>(row_ptr, bsums, Nn);
    scatter_kernel<<<(E / 4 + 255) / 256, 256, 0, stream>>>(src, dst, row_ptr, erank, esrc, E);

    const int gm32 = (Nn + 31) / 32;    // 1563

    // Layer 1 (fused gather+gemm): [mean(x_nbr) | x] -> 256, relu; bf16 + fp8 out
    fused_gemm_kernel<128, 128, 256, true, false, false, true>
        <<<gm32, 256, 0, stream>>>(xb, xb, row_ptr, esrc,
                                   (const short8x*)wt1h, b1, h1b, h1f8,
                                   nullptr, nullptr, nullptr, Nn);

    // Layer 2 (fused gather+gemm, fp8 gather): [mean(h1_nbr) | h1] -> 256, relu;
    // fused tu epilogue (no h2 materialized)
    fused_gemm_kernel<256, 256, 256, true, true, true, false>
        <<<gm32, 256, 0, stream>>>(h1f8, h1b, row_ptr, esrc,
                                   (const short8x*)wt2h, b2, nullptr, nullptr,
                                   Wc, bc, tu, Nn);

    // out = mean-gather(t) + u
    final_out_kernel<<<512, 256, 0, stream>>>(tu, row_ptr, esrc, (float*)d_out, Nn);
}

// Round 26
// 154.454 us; speedup vs baseline: 1.0921x; 1.0921x over previous
//
#include <hip/hip_runtime.h>
#include <hip/hip_fp8.h>

// ---------------------------------------------------------------------------
// GraphSAGE forward: 3x SAGEConv(mean) + ReLU(1,2) + final 128->2 projection.
// BEST VALIDATED CONFIG (round 23, 154.6us) — exact revert.
// Pure bf16 (1-term) MFMA numerics; layer-2 gather reads fp8-e4m3 h1 copy
// (HW v_cvt_pk_f32_fp8 decode / v_cvt_pk_fp8_f32 encode).
// FUSED gather+GEMM per BM=32 block; 4-edge batched gather with index
// prefetch; setprio(1) around MFMA K-loop.
// Layer-1 epilogue: C staged in LDS (sA overlay + sF8), written as contiguous
// full-line spans. CSR: count-atomicAdd return saved as erank -> atomic-free
// scatter. Layer3+out-proj collapsed to [256][4] Wc; tu fused into GEMM-2.
// REFUTED experiments: BM=16 (R24: W-traffic doubling), launch_bounds(256,6)
// (R25: VGPR bloat 60->80, occupancy fell).
// ---------------------------------------------------------------------------

constexpr int D_IN  = 128;
constexpr int D_HID = 256;

typedef __attribute__((ext_vector_type(8))) short short8x;
typedef __attribute__((ext_vector_type(4))) float f32x4;
typedef __attribute__((ext_vector_type(2))) float f32x2;

__device__ inline unsigned bf16_rne(float f) {
    unsigned u = __float_as_uint(f);
    return (u + 0x7fffu + ((u >> 16) & 1u)) >> 16;
}

// ---------------- fused setup ----------------

__device__ inline void prep_wt_elem(const float* __restrict__ Wl,
                                    const float* __restrict__ Wr,
                                    int K1, int K2, int Nc, int i,
                                    short* __restrict__ WTh) {
    const int KE = K1 + K2;
    const int KSTEPS = KE / 32;
    int e = i & 7;
    int t = i >> 3;
    int l = t & 63;
    int t2 = t >> 6;
    int k32 = t2 % KSTEPS;
    int n16 = t2 / KSTEPS;
    int n = n16 * 16 + (l & 15);
    int k = k32 * 32 + (l >> 4) * 8 + e;
    float w = (k < K1) ? Wl[(size_t)k * Nc + n] : Wr[(size_t)(k - K1) * Nc + n];
    WTh[i] = (short)bf16_rne(w);
}

__global__ __launch_bounds__(256) void setup_kernel(
    const float* __restrict__ Wl1, const float* __restrict__ Wr1,
    short* __restrict__ wt1h,
    const float* __restrict__ Wl2, const float* __restrict__ Wr2,
    short* __restrict__ wt2h,
    const float* __restrict__ Wl3, const float* __restrict__ Wr3,
    const float* __restrict__ b3, const float* __restrict__ Wout,
    const float* __restrict__ bout, float* __restrict__ Wc, float* __restrict__ bc,
    const float* __restrict__ x, unsigned short* __restrict__ xb,
    const int* __restrict__ dst, int* __restrict__ cnt, int* __restrict__ erank,
    int Nn, int E) {
    const int gtid = blockIdx.x * blockDim.x + threadIdx.x;
    const int gs = gridDim.x * blockDim.x;

    const int n8 = Nn * D_IN / 8;
    for (int i = gtid; i < n8; i += gs) {
        const float4* p = (const float4*)(x + (size_t)i * 8);
        float4 v0 = p[0], v1 = p[1];
        float f[8] = {v0.x, v0.y, v0.z, v0.w, v1.x, v1.y, v1.z, v1.w};
        unsigned h[8];
        #pragma unroll
        for (int j = 0; j < 8; ++j) h[j] = bf16_rne(f[j]);
        uint4 qh;
        qh.x = h[0] | (h[1] << 16); qh.y = h[2] | (h[3] << 16);
        qh.z = h[4] | (h[5] << 16); qh.w = h[6] | (h[7] << 16);
        *(uint4*)(xb + (size_t)i * 8) = qh;
    }

    // degree count; atomic return value = within-bucket rank (free)
    for (int i = gtid; i < E; i += gs)
        erank[i] = atomicAdd(&cnt[dst[i]], 1);

    for (int i = gtid; i < 256 * 256; i += gs)
        prep_wt_elem(Wl1, Wr1, 128, 128, 256, i, wt1h);
    for (int i = gtid; i < 256 * 512; i += gs)
        prep_wt_elem(Wl2, Wr2, 256, 256, 256, i, wt2h);

    if (gtid < 1024 * 16) {
        int d = gtid >> 4, sl = gtid & 15;
        int hh = d >> 2, c = d & 3;
        const float* Ws = (c < 2) ? Wl3 : Wr3;
        int o = c & 1;
        float s = 0.f;
        #pragma unroll
        for (int e = 0; e < 8; ++e) {
            int k = sl * 8 + e;
            s += Ws[hh * 128 + k] * Wout[k * 2 + o];
        }
        #pragma unroll
        for (int mk = 8; mk >= 1; mk >>= 1) s += __shfl_xor(s, mk, 16);
        if (sl == 0) Wc[d] = s;
    }
    if (gtid >= 16384 && gtid < 16416) {
        int o = (gtid >> 4) & 1, sl = gtid & 15;
        float s = 0.f;
        #pragma unroll
        for (int e = 0; e < 8; ++e) {
            int k = sl * 8 + e;
            s += b3[k] * Wout[k * 2 + o];
        }
        #pragma unroll
        for (int mk = 8; mk >= 1; mk >>= 1) s += __shfl_xor(s, mk, 16);
        if (sl == 0) bc[o] = s + bout[o];
    }
}

// ---------------- CSR scan + atomic-free scatter ----------------

__global__ __launch_bounds__(1024) void scan_local_kernel(
    const int* __restrict__ cnt, int* __restrict__ row_ptr,
    int* __restrict__ bsums, int Nn) {
    __shared__ int wsum[16];
    const int tid = threadIdx.x, lane = tid & 63, wid = tid >> 6;
    const int idx0 = blockIdx.x * 4096 + tid * 4;
    int v[4];
    #pragma unroll
    for (int j = 0; j < 4; ++j) {
        int idx = idx0 + j;
        v[j] = (idx < Nn) ? cnt[idx] : 0;
    }
    int s = v[0] + v[1] + v[2] + v[3];
    int xi = s;
    #pragma unroll
    for (int o = 1; o < 64; o <<= 1) {
        int t = __shfl_up(xi, o, 64);
        if (lane >= o) xi += t;
    }
    if (lane == 63) wsum[wid] = xi;
    __syncthreads();
    if (wid == 0) {
        int t = (lane < 16) ? wsum[lane] : 0;
        #pragma unroll
        for (int o = 1; o < 16; o <<= 1) {
            int u = __shfl_up(t, o, 64);
            if (lane >= o) t += u;
        }
        if (lane < 16) wsum[lane] = t;
    }
    __syncthreads();
    int off = (wid ? wsum[wid - 1] : 0) + xi - s;
    int run = off;
    #pragma unroll
    for (int j = 0; j < 4; ++j) {
        int idx = idx0 + j;
        if (idx <= Nn) row_ptr[idx] = run;
        run += v[j];
    }
    if (tid == 0) bsums[blockIdx.x] = wsum[15];
}

__global__ __launch_bounds__(1024) void scan_add_kernel(
    int* __restrict__ row_ptr, const int* __restrict__ bsums, int Nn) {
    __shared__ int sbase;
    const int b = blockIdx.x;
    if (threadIdx.x == 0) {
        int s = 0;
        for (int i = 0; i < b; ++i) s += bsums[i];
        sbase = s;
    }
    __syncthreads();
    const int base = sbase;
    const int idx0 = b * 4096 + threadIdx.x * 4;
    #pragma unroll
    for (int j = 0; j < 4; ++j) {
        int idx = idx0 + j;
        if (idx <= Nn) row_ptr[idx] += base;
    }
}

// atomic-free: position = row_ptr[dst] + erank (rank saved during count).
__global__ __launch_bounds__(256) void scatter_kernel(
    const int* __restrict__ src, const int* __restrict__ dst,
    const int* __restrict__ row_ptr, const int* __restrict__ erank,
    int* __restrict__ esrc, int E) {
    int i0 = (blockIdx.x * blockDim.x + threadIdx.x) * 4;
    if (i0 >= E) return;
    int n = E - i0; if (n > 4) n = 4;
    int s[4], d[4], r[4], b[4];
    for (int j = 0; j < n; ++j) { s[j] = src[i0 + j]; d[j] = dst[i0 + j]; r[j] = erank[i0 + j]; }
    for (int j = 0; j < n; ++j) b[j] = row_ptr[d[j]];
    for (int j = 0; j < n; ++j) esrc[b[j] + r[j]] = s[j];
}

// ---------------- gather decode helpers ----------------

__device__ inline void addbf8(const uint4& q, float* a) {
    a[0] += __uint_as_float(q.x << 16); a[1] += __uint_as_float(q.x & 0xFFFF0000u);
    a[2] += __uint_as_float(q.y << 16); a[3] += __uint_as_float(q.y & 0xFFFF0000u);
    a[4] += __uint_as_float(q.z << 16); a[5] += __uint_as_float(q.z & 0xFFFF0000u);
    a[6] += __uint_as_float(q.w << 16); a[7] += __uint_as_float(q.w & 0xFFFF0000u);
}

__device__ inline void addf8w(unsigned u, float* a) {
    f32x2 lo = __builtin_amdgcn_cvt_pk_f32_fp8((int)u, false);
    f32x2 hi = __builtin_amdgcn_cvt_pk_f32_fp8((int)u, true);
    a[0] += lo.x; a[1] += lo.y; a[2] += hi.x; a[3] += hi.y;
}

__device__ inline void addf8x16(const uint4& q, float* a) {
    addf8w(q.x, a + 0); addf8w(q.y, a + 4); addf8w(q.z, a + 8); addf8w(q.w, a + 12);
}

// ---------------- FUSED gather + bf16 MFMA GEMM, BM=32 ----------------
// Phase 1: gather-mean into sA[:, 0:K1] (bf16, XOR-swizzled chunks), 4-edge
// batched with next-batch index prefetch. Phase 2: self rows. One barrier.
// Phase 3: barrier-free K-loop (setprio(1)), B reg-prefetched 1 step ahead.
// Epilogue (!TU): stage C tile in LDS (sA overlay bf16 + sF8 fp8), write
// contiguous full-line spans. (TU): sRed overlaid on sA.
// Swizzle: chunk c (16B) of row r stored at p = (c&~7) | ((c&7)^(r&7)).

template <int K1, int K2, int N, bool RELU, bool TU, bool F8G, bool F8OUT>
__global__ __launch_bounds__(256, 4) void fused_gemm_kernel(
    const void* __restrict__ gsrc, const unsigned short* __restrict__ self,
    const int* __restrict__ row_ptr, const int* __restrict__ esrc,
    const short8x* __restrict__ WTh, const float* __restrict__ bias,
    unsigned short* __restrict__ C, unsigned char* __restrict__ C8,
    const float* __restrict__ Wc, const float* __restrict__ bc,
    float* __restrict__ tuout, int M) {
    constexpr int KEFF = K1 + K2;
    constexpr int KS32 = KEFF / 32;
    constexpr int NC1 = K1 / 8;       // gather-half chunks per row
    constexpr int NC2 = K2 / 8;       // self-half chunks per row
    __shared__ __attribute__((aligned(16))) unsigned short sA[32][KEFF];
    __shared__ __attribute__((aligned(16))) unsigned char sF8[F8OUT ? 32 * N : 16];
    float4* sRed = (float4*)&sA[0][0];          // TU overlay (after K-loop)
    unsigned short* sC = &sA[0][0];             // !TU overlay (after K-loop)
    const int tid = threadIdx.x, lane = tid & 63, wid = tid >> 6;
    const int bm = blockIdx.x * 32;

    // ---- phase 1: gather-mean into sA[:, 0:K1] (16 lanes per node) ----
    #pragma unroll
    for (int pass = 0; pass < 2; ++pass) {
        const int nl = pass * 16 + wid * 4 + (lane >> 4);
        const int node = bm + nl;
        const int sl = lane & 15;
        if constexpr (!F8G) {
            float a0[8] = {}, a1[8] = {}, a2[8] = {}, a3[8] = {};
            float inv = 1.0f;
            if (node < M) {
                int beg = row_ptr[node], end = row_ptr[node + 1];
                const unsigned short* xg = (const unsigned short*)gsrc;
                int e = beg;
                const int nb4 = (end - beg) >> 2;
                if (nb4 > 0) {
                    int s0 = esrc[e], s1 = esrc[e + 1], s2 = esrc[e + 2], s3 = esrc[e + 3];
                    for (int b = 0; b < nb4; ++b) {
                        int t0 = s0, t1 = s1, t2 = s2, t3 = s3;
                        int en = e + 4;
                        if (b + 1 < nb4) {   // prefetch next batch indices
                            s0 = esrc[en]; s1 = esrc[en + 1];
                            s2 = esrc[en + 2]; s3 = esrc[en + 3];
                        }
                        uint4 q0 = *(const uint4*)(xg + (size_t)t0 * K1 + sl * 8);
                        uint4 q1 = *(const uint4*)(xg + (size_t)t1 * K1 + sl * 8);
                        uint4 q2 = *(const uint4*)(xg + (size_t)t2 * K1 + sl * 8);
                        uint4 q3 = *(const uint4*)(xg + (size_t)t3 * K1 + sl * 8);
                        addbf8(q0, a0); addbf8(q1, a1); addbf8(q2, a2); addbf8(q3, a3);
                        e = en;
                    }
                }
                for (; e < end; ++e) {
                    uint4 q0 = *(const uint4*)(xg + (size_t)esrc[e] * K1 + sl * 8);
                    addbf8(q0, a0);
                }
                inv = 1.0f / fmaxf((float)(end - beg), 1.0f);
            }
            unsigned h[8];
            #pragma unroll
            for (int i = 0; i < 8; ++i)
                h[i] = bf16_rne((a0[i] + a1[i] + a2[i] + a3[i]) * inv);
            uint4 qh;
            qh.x = h[0] | (h[1] << 16); qh.y = h[2] | (h[3] << 16);
            qh.z = h[4] | (h[5] << 16); qh.w = h[6] | (h[7] << 16);
            int p = (sl & 8) | ((sl & 7) ^ (nl & 7));
            *(uint4*)&sA[nl][p * 8] = qh;
        } else {
            float a0[16] = {}, a1[16] = {};
            float inv = 1.0f;
            if (node < M) {
                int beg = row_ptr[node], end = row_ptr[node + 1];
                const unsigned char* xg = (const unsigned char*)gsrc;
                int e = beg;
                const int nb4 = (end - beg) >> 2;
                if (nb4 > 0) {
                    int s0 = esrc[e], s1 = esrc[e + 1], s2 = esrc[e + 2], s3 = esrc[e + 3];
                    for (int b = 0; b < nb4; ++b) {
                        int t0 = s0, t1 = s1, t2 = s2, t3 = s3;
                        int en = e + 4;
                        if (b + 1 < nb4) {   // prefetch next batch indices
                            s0 = esrc[en]; s1 = esrc[en + 1];
                            s2 = esrc[en + 2]; s3 = esrc[en + 3];
                        }
                        uint4 q0 = *(const uint4*)(xg + (size_t)t0 * K1 + sl * 16);
                        uint4 q1 = *(const uint4*)(xg + (size_t)t1 * K1 + sl * 16);
                        uint4 q2 = *(const uint4*)(xg + (size_t)t2 * K1 + sl * 16);
                        uint4 q3 = *(const uint4*)(xg + (size_t)t3 * K1 + sl * 16);
                        addf8x16(q0, a0); addf8x16(q1, a1);
                        addf8x16(q2, a0); addf8x16(q3, a1);
                        e = en;
                    }
                }
                for (; e < end; ++e) {
                    uint4 q0 = *(const uint4*)(xg + (size_t)esrc[e] * K1 + sl * 16);
                    addf8x16(q0, a0);
                }
                inv = 1.0f / fmaxf((float)(end - beg), 1.0f);
            }
            unsigned h[16];
            #pragma unroll
            for (int i = 0; i < 16; ++i)
                h[i] = bf16_rne((a0[i] + a1[i]) * inv);
            uint4 qa, qb;
            qa.x = h[0]  | (h[1]  << 16); qa.y = h[2]  | (h[3]  << 16);
            qa.z = h[4]  | (h[5]  << 16); qa.w = h[6]  | (h[7]  << 16);
            qb.x = h[8]  | (h[9]  << 16); qb.y = h[10] | (h[11] << 16);
            qb.z = h[12] | (h[13] << 16); qb.w = h[14] | (h[15] << 16);
            int c0 = sl * 2, c1 = sl * 2 + 1;
            int p0 = (c0 & ~7) | ((c0 & 7) ^ (nl & 7));
            int p1 = (c1 & ~7) | ((c1 & 7) ^ (nl & 7));
            *(uint4*)&sA[nl][p0 * 8] = qa;
            *(uint4*)&sA[nl][p1 * 8] = qb;
        }
    }

    // ---- phase 2: self rows into sA[:, K1:] ----
    {
        const int row = tid >> 3, sub = tid & 7;
        int grow = bm + row; if (grow >= M) grow = M - 1;
        #pragma unroll
        for (int i = 0; i < NC2 / 8; ++i) {
            int cg = sub + 8 * i;
            uint4 v = *(const uint4*)(self + (size_t)grow * K2 + cg * 8);
            int c = NC1 + cg;
            int p = (c & ~7) | ((c & 7) ^ (row & 7));
            *(uint4*)&sA[row][p * 8] = v;
        }
    }
    __syncthreads();

    // ---- phase 3: barrier-free K-loop (MFMA priority boost) ----
    auto loadB = [&](int ks, short8x* bh) {
        #pragma unroll
        for (int n = 0; n < 4; ++n)
            bh[n] = WTh[((size_t)(wid * 4 + n) * KS32 + ks) * 64 + lane];
    };

    f32x4 acc[2][4];
    #pragma unroll
    for (int m = 0; m < 2; ++m)
        #pragma unroll
        for (int n = 0; n < 4; ++n)
            acc[m][n] = (f32x4){0.f, 0.f, 0.f, 0.f};

    short8x bhC[4], bhN[4];
    loadB(0, bhC);

    __builtin_amdgcn_s_setprio(1);
    #pragma unroll
    for (int ks = 0; ks < KS32; ++ks) {
        if (ks + 1 < KS32) loadB(ks + 1, bhN);
        short8x a[2];
        #pragma unroll
        for (int m = 0; m < 2; ++m) {
            const int row = m * 16 + (lane & 15);
            const int c = ks * 4 + (lane >> 4);
            const int p = (c & ~7) | ((c & 7) ^ (lane & 7));   // row&7 == lane&7
            a[m] = *(const short8x*)&sA[row][p * 8];
        }
        #pragma unroll
        for (int m = 0; m < 2; ++m)
            #pragma unroll
            for (int n = 0; n < 4; ++n)
                acc[m][n] = __builtin_amdgcn_mfma_f32_16x16x32_bf16(a[m], bhC[n], acc[m][n], 0, 0, 0);
        if (ks + 1 < KS32) {
            #pragma unroll
            for (int n = 0; n < 4; ++n) bhC[n] = bhN[n];  // renamed by unroll
        }
    }
    __builtin_amdgcn_s_setprio(0);

    float bv[4];
    #pragma unroll
    for (int n = 0; n < 4; ++n) bv[n] = bias[wid * 64 + n * 16 + (lane & 15)];

    if constexpr (!TU) {
        __syncthreads();   // sA reads done; overlay as staged C tile
        #pragma unroll
        for (int n = 0; n < 4; ++n) {
            const int col = wid * 64 + n * 16 + (lane & 15);
            #pragma unroll
            for (int m = 0; m < 2; ++m) {
                #pragma unroll
                for (int j = 0; j < 4; ++j) {
                    int rl = m * 16 + (lane >> 4) * 4 + j;
                    float v = acc[m][n][j] + bv[n];
                    if (RELU) v = fmaxf(v, 0.f);
                    sC[rl * N + col] = (unsigned short)bf16_rne(v);
                    if (F8OUT) {
                        int pk = __builtin_amdgcn_cvt_pk_fp8_f32(v, v, 0, false);
                        sF8[rl * N + col] = (unsigned char)(pk & 0xff);
                    }
                }
            }
        }
        __syncthreads();
        // coalesced full-line write-out of the contiguous block tile
        const int vrows = (M - bm < 32) ? (M - bm) : 32;
        const int tot = vrows * N;                    // elements
        const size_t base = (size_t)bm * N;
        for (int i = tid * 8; i < tot; i += 256 * 8)
            *(uint4*)(C + base + i) = *(const uint4*)(sC + i);
        if (F8OUT) {
            for (int i = tid * 16; i < tot; i += 256 * 16)
                *(uint4*)(C8 + base + i) = *(const uint4*)(sF8 + i);
        }
    } else {
        float4 wcv[4];
        #pragma unroll
        for (int n = 0; n < 4; ++n)
            wcv[n] = *(const float4*)(Wc + (size_t)(wid * 64 + n * 16 + (lane & 15)) * 4);
        __syncthreads();   // all waves done reading sA before sRed overlay write
        #pragma unroll
        for (int m = 0; m < 2; ++m) {
            #pragma unroll
            for (int j = 0; j < 4; ++j) {
                float4 p = make_float4(0.f, 0.f, 0.f, 0.f);
                #pragma unroll
                for (int n = 0; n < 4; ++n) {
                    float v = acc[m][n][j] + bv[n];
                    if (RELU) v = fmaxf(v, 0.f);
                    p.x += v * wcv[n].x; p.y += v * wcv[n].y;
                    p.z += v * wcv[n].z; p.w += v * wcv[n].w;
                }
                #pragma unroll
                for (int mk = 8; mk >= 1; mk >>= 1) {
                    p.x += __shfl_xor(p.x, mk, 64);
                    p.y += __shfl_xor(p.y, mk, 64);
                    p.z += __shfl_xor(p.z, mk, 64);
                    p.w += __shfl_xor(p.w, mk, 64);
                }
                if ((lane & 15) == 0)
                    sRed[wid * 32 + m * 16 + (lane >> 4) * 4 + j] = p;
            }
        }
        __syncthreads();
        if (tid < 32) {
            int row = bm + tid;
            float4 a = sRed[0 * 32 + tid], b2 = sRed[1 * 32 + tid];
            float4 c2 = sRed[2 * 32 + tid], d2 = sRed[3 * 32 + tid];
            float4 t;
            t.x = a.x + b2.x + c2.x + d2.x;
            t.y = a.y + b2.y + c2.y + d2.y;
            t.z = a.z + b2.z + c2.z + d2.z + bc[0];
            t.w = a.w + b2.w + c2.w + d2.w + bc[1];
            if (row < M) *(float4*)(tuout + (size_t)row * 4) = t;
        }
    }
}

// ---------------- out_i = mean_j t_j + u_i  (D=2 gather, L2-resident) ------

__global__ __launch_bounds__(256) void final_out_kernel(
    const float* __restrict__ tu, const int* __restrict__ row_ptr,
    const int* __restrict__ esrc, float* __restrict__ out, int Nn) {
    int stride = gridDim.x * blockDim.x;
    for (int i = blockIdx.x * blockDim.x + threadIdx.x; i < Nn; i += stride) {
        int beg = row_ptr[i], end = row_ptr[i + 1];
        float s0 = 0.f, s1 = 0.f;
        for (int e = beg; e < end; ++e) {
            int s = esrc[e];
            float2 tv = *(const float2*)(tu + (size_t)s * 4);
            s0 += tv.x; s1 += tv.y;
        }
        float inv = 1.0f / fmaxf((float)(end - beg), 1.0f);
        float u0 = tu[(size_t)i * 4 + 2], u1 = tu[(size_t)i * 4 + 3];
        *(float2*)(out + (size_t)i * 2) = make_float2(s0 * inv + u0, s1 * inv + u1);
    }
}

// ---------------- launch ----------------

extern "C" void kernel_launch(void* const* d_in, const int* in_sizes, int n_in,
                              void* d_out, int out_size, void* d_ws, size_t ws_size,
                              hipStream_t stream) {
    const float* x    = (const float*)d_in[0];
    const int*   ei   = (const int*)d_in[1];
    const float* Wl1  = (const float*)d_in[2];
    const float* Wr1  = (const float*)d_in[3];
    const float* b1   = (const float*)d_in[4];
    const float* Wl2  = (const float*)d_in[5];
    const float* Wr2  = (const float*)d_in[6];
    const float* b2   = (const float*)d_in[7];
    const float* Wl3  = (const float*)d_in[8];
    const float* Wr3  = (const float*)d_in[9];
    const float* b3   = (const float*)d_in[10];
    const float* Wout = (const float*)d_in[11];
    const float* bout = (const float*)d_in[12];

    const int Nn = in_sizes[0] / D_IN;     // 50000
    const int E  = in_sizes[1] / 2;        // 600000

    char* ws = (char*)d_ws;
    size_t off = 0;
    auto alloc = [&](size_t b) { size_t o = off; off = (off + b + 255) & ~(size_t)255; return o; };

    unsigned short* xb    = (unsigned short*)(ws + alloc((size_t)Nn * D_IN * 2));
    int*   row_ptr = (int*)(ws + alloc((size_t)(Nn + 1) * 4));
    int*   cnt     = (int*)(ws + alloc((size_t)Nn * 4));
    int*   erank   = (int*)(ws + alloc((size_t)E * 4));
    int*   bsums   = (int*)(ws + alloc((size_t)256 * 4));
    int*   esrc    = (int*)(ws + alloc((size_t)E * 4));
    unsigned short* h1b   = (unsigned short*)(ws + alloc((size_t)Nn * D_HID * 2));
    unsigned char*  h1f8  = (unsigned char*)(ws + alloc((size_t)Nn * D_HID));
    float* tu      = (float*)(ws + alloc((size_t)Nn * 4 * 4));
    float* Wc      = (float*)(ws + alloc((size_t)256 * 4 * 4));
    float* bc      = (float*)(ws + alloc((size_t)2 * 4));
    short* wt1h    = (short*)(ws + alloc((size_t)256 * 256 * 2));
    short* wt2h    = (short*)(ws + alloc((size_t)256 * 512 * 2));

    const int* src = ei;
    const int* dst = ei + E;

    hipMemsetAsync(cnt, 0, (size_t)Nn * 4, stream);

    setup_kernel<<<2048, 256, 0, stream>>>(
        Wl1, Wr1, wt1h, Wl2, Wr2, wt2h,
        Wl3, Wr3, b3, Wout, bout, Wc, bc,
        x, xb, dst, cnt, erank, Nn, E);

    const int nb = (Nn + 1 + 4095) / 4096;   // 13
    scan_local_kernel<<<nb, 1024, 0, stream>>>(cnt, row_ptr, bsums, Nn);
    scan_add_kernel<<<nb, 1024, 0, stream>>>(row_ptr, bsums, Nn);
    scatter_kernel<<<(E / 4 + 255) / 256, 256, 0, stream>>>(src, dst, row_ptr, erank, esrc, E);

    const int gm32 = (Nn + 31) / 32;    // 1563

    // Layer 1 (fused gather+gemm): [mean(x_nbr) | x] -> 256, relu; bf16 + fp8 out
    fused_gemm_kernel<128, 128, 256, true, false, false, true>
        <<<gm32, 256, 0, stream>>>(xb, xb, row_ptr, esrc,
                                   (const short8x*)wt1h, b1, h1b, h1f8,
                                   nullptr, nullptr, nullptr, Nn);

    // Layer 2 (fused gather+gemm, fp8 gather): [mean(h1_nbr) | h1] -> 256, relu;
    // fused tu epilogue (no h2 materialized)
    fused_gemm_kernel<256, 256, 256, true, true, true, false>
        <<<gm32, 256, 0, stream>>>(h1f8, h1b, row_ptr, esrc,
                                   (const short8x*)wt2h, b2, nullptr, nullptr,
                                   Wc, bc, tu, Nn);

    // out = mean-gather(t) + u
    final_out_kernel<<<512, 256, 0, stream>>>(tu, row_ptr, esrc, (float*)d_out, Nn);
}